// Round 25
// baseline (93.275 us; speedup 1.0000x reference)
//
#include <hip/hip_runtime.h>
#include <hip/hip_bf16.h>
#include <math.h>

#define BB   8
#define NN   2048
#define BN   (BB * NN)
#define CINC 128
#define COU  256
#define KNNK 16
#define REVCAP 64
#define QG   32            // queries per knn block

typedef __bf16 bf16x8 __attribute__((ext_vector_type(8)));
typedef float  f32x4  __attribute__((ext_vector_type(4)));

#define UMED3(dst, a, bb_, c) asm("v_med3_u32 %0, %1, %2, %3" : "=v"(dst) : "v"(a), "v"(bb_), "v"(c))

// 16 sorted regs t0<=..<=t15 (t8..t15 only used from the fold onward).
#define TOP_DECL \
    unsigned int t0=~0u,t1=~0u,t2=~0u,t3=~0u,t4=~0u,t5=~0u,t6=~0u,t7=~0u, \
                 t8=~0u,t9=~0u,t10=~0u,t11=~0u,t12=~0u,t13=~0u,t14=~0u,t15=~0u;

// 16-deep insert (merge/fallback): 15 med3 + 1 min.
#define TOP_INSERT(u) {                     \
    UMED3(t15, t14, t15, (u));              \
    UMED3(t14, t13, t14, (u));              \
    UMED3(t13, t12, t13, (u));              \
    UMED3(t12, t11, t12, (u));              \
    UMED3(t11, t10, t11, (u));              \
    UMED3(t10, t9,  t10, (u));              \
    UMED3(t9,  t8,  t9,  (u));              \
    UMED3(t8,  t7,  t8,  (u));              \
    UMED3(t7,  t6,  t7,  (u));              \
    UMED3(t6,  t5,  t6,  (u));              \
    UMED3(t5,  t4,  t5,  (u));              \
    UMED3(t4,  t3,  t4,  (u));              \
    UMED3(t3,  t2,  t3,  (u));              \
    UMED3(t2,  t1,  t2,  (u));              \
    UMED3(t1,  t0,  t1,  (u));              \
    t0 = ((u) < t0) ? (u) : t0;             \
}

// 8-deep insert (hot scan): 7 med3 + 1 min.
#define TOP8_INSERT(u) {                    \
    UMED3(t7,  t6,  t7,  (u));              \
    UMED3(t6,  t5,  t6,  (u));              \
    UMED3(t5,  t4,  t5,  (u));              \
    UMED3(t4,  t3,  t4,  (u));              \
    UMED3(t3,  t2,  t3,  (u));              \
    UMED3(t2,  t1,  t2,  (u));              \
    UMED3(t1,  t0,  t1,  (u));              \
    t0 = ((u) < t0) ? (u) : t0;             \
}

// dist arithmetic: bit-identical to the verified R1-R23 formula.
static __device__ __forceinline__ unsigned int dist_du(float qx, float qy, float qz,
                                                       float qsq, float4 c) {
    float dot = fmaf(qz, c.z, fmaf(qy, c.y, __fmul_rn(qx, c.x)));
    float d = __fsub_rn(__fadd_rn(qsq, c.w), __fmul_rn(2.0f, dot));
    unsigned int du = __float_as_uint(d);
    du ^= (unsigned int)((int)du >> 31) | 0x80000000u;
    return du;
}

// ---------------- setup: transpose + prep weights + zero rcnt (verified R23) ----------------
__global__ __launch_bounds__(256) void setup_kernel(const float* __restrict__ feat,
                                                    __bf16* __restrict__ fTB,
                                                    const float* __restrict__ Wspec,
                                                    const float* __restrict__ Wlow,
                                                    const float* __restrict__ Whigh,
                                                    const float* __restrict__ blow,
                                                    const float* __restrict__ bhigh,
                                                    __bf16* __restrict__ WspecB,
                                                    __bf16* __restrict__ WcB,
                                                    float* __restrict__ bc,
                                                    int* __restrict__ rcnt) {
    __shared__ float t[32][33];
    int bid = blockIdx.x;
    int tx = threadIdx.x, ty = threadIdx.y;  // (32,8)
    if (bid < 2048) {
        int b  = bid >> 8;
        int r  = bid & 255;
        int n0 = (r & 63) * 32;
        int c0 = (r >> 6) * 32;
#pragma unroll
        for (int i = 0; i < 4; i++)
            t[ty + i * 8][tx] = feat[((size_t)b * CINC + c0 + ty + i * 8) * NN + n0 + tx];
        __syncthreads();
#pragma unroll
        for (int i = 0; i < 4; i++)
            fTB[((size_t)b * NN + n0 + ty + i * 8) * CINC + c0 + tx] = (__bf16)t[tx][ty + i * 8];
    } else {
        int r = bid - 2048;                  // 0..127
        int i = r * 256 + ty * 32 + tx;
        if (i < COU * CINC) WspecB[i] = (__bf16)Wspec[i];
        if (i < 128 * COU) {
            WcB[i] = (__bf16)Wlow[i];
            WcB[128 * COU + i] = (__bf16)Whigh[i];
        }
        if (i < 128) { bc[i] = blow[i]; bc[128 + i] = bhigh[i]; }
        rcnt[r * 128 + (ty * 32 + tx) % 128] = 0;
    }
}

// ---------------- KNN fused v6 (verified R22/R23, unchanged) ----------------
__global__ __launch_bounds__(1024, 8) void knn_fused_kernel(const float* __restrict__ xyz,
                                                            int* __restrict__ knn_idx,
                                                            int* __restrict__ revcnt,
                                                            int* __restrict__ rev) {
    __shared__ float4 cand[NN];                     // 32 KB
    __shared__ unsigned int mbuf[8][KNNK][QG];      // 16 KB
    __shared__ unsigned int Tq[QG];
    __shared__ int cntless[QG];
    __shared__ int tiecnt[QG];
    __shared__ unsigned short tieidx[16][QG];
    __shared__ unsigned short sel[KNNK][QG];

    int b = blockIdx.y;
    int lane = threadIdx.x & 63;
    int w = threadIdx.x >> 6;
    int q32 = lane & 31;
    int qh = lane >> 5;
    int q = blockIdx.x * QG + q32;
    int bq = b * NN + q;

    const float* xb = xyz + (size_t)b * 3 * NN;
    for (int t = threadIdx.x; t < NN; t += 1024) {
        float x = xb[t], y = xb[NN + t], z = xb[2 * NN + t];
        float sq = __fadd_rn(__fadd_rn(__fmul_rn(x, x), __fmul_rn(y, y)), __fmul_rn(z, z));
        cand[t] = make_float4(x, y, z, sq);
    }
    if (threadIdx.x < QG) { cntless[threadIdx.x] = 0; tiecnt[threadIdx.x] = 0; }
    __syncthreads();

    float qx = xb[q], qy = xb[NN + q], qz = xb[2 * NN + q];
    float qsq = __fadd_rn(__fadd_rn(__fmul_rn(qx, qx), __fmul_rn(qy, qy)), __fmul_rn(qz, qz));

    int segbase = w * 128 + qh * 64;

    TOP_DECL
    for (int i = 0; i < 64; i += 4) {   // phase A: 8-deep scan
        float4 c0 = cand[segbase + i + 0];
        float4 c1 = cand[segbase + i + 1];
        float4 c2 = cand[segbase + i + 2];
        float4 c3 = cand[segbase + i + 3];
        unsigned int d0 = dist_du(qx, qy, qz, qsq, c0);
        unsigned int d1 = dist_du(qx, qy, qz, qsq, c1);
        unsigned int d2 = dist_du(qx, qy, qz, qsq, c2);
        unsigned int d3 = dist_du(qx, qy, qz, qsq, c3);
        TOP8_INSERT(d0)
        TOP8_INSERT(d1)
        TOP8_INSERT(d2)
        TOP8_INSERT(d3)
    }

    {   // intra-wave fold
        unsigned int s0 = __shfl_xor(t0, 32), s1 = __shfl_xor(t1, 32);
        unsigned int s2 = __shfl_xor(t2, 32), s3 = __shfl_xor(t3, 32);
        unsigned int s4 = __shfl_xor(t4, 32), s5 = __shfl_xor(t5, 32);
        unsigned int s6 = __shfl_xor(t6, 32), s7 = __shfl_xor(t7, 32);
        TOP_INSERT(s0) TOP_INSERT(s1) TOP_INSERT(s2) TOP_INSERT(s3)
        TOP_INSERT(s4) TOP_INSERT(s5) TOP_INSERT(s6) TOP_INSERT(s7)
    }

    for (int s = 8; s >= 1; s >>= 1) {  // tree merge
        if (w >= s && w < 2 * s && lane < 32) {
            int j = w - s;
            mbuf[j][0][q32] = t0;   mbuf[j][1][q32] = t1;
            mbuf[j][2][q32] = t2;   mbuf[j][3][q32] = t3;
            mbuf[j][4][q32] = t4;   mbuf[j][5][q32] = t5;
            mbuf[j][6][q32] = t6;   mbuf[j][7][q32] = t7;
            mbuf[j][8][q32] = t8;   mbuf[j][9][q32] = t9;
            mbuf[j][10][q32] = t10; mbuf[j][11][q32] = t11;
            mbuf[j][12][q32] = t12; mbuf[j][13][q32] = t13;
            mbuf[j][14][q32] = t14; mbuf[j][15][q32] = t15;
        }
        __syncthreads();
        if (w < s) {
#pragma unroll
            for (int k = 0; k < KNNK; k++) {
                unsigned int u = mbuf[w][k][q32];
                TOP_INSERT(u)
            }
        }
        __syncthreads();
    }
    if (w == 0 && lane < 32) Tq[q32] = t15;
    __syncthreads();

    {   // emission
        unsigned int T = Tq[q32];
        for (int i = 0; i < 64; i++) {
            float4 c = cand[segbase + i];
            unsigned int du = dist_du(qx, qy, qz, qsq, c);
            if (du < T) {
                int slot = atomicAdd(&cntless[q32], 1);
                if (slot < 16) sel[slot][q32] = (unsigned short)(segbase + i);
            } else if (du == T) {
                int t = atomicAdd(&tiecnt[q32], 1);
                if (t < 16) tieidx[t][q32] = (unsigned short)(segbase + i);
            }
        }
    }
    __syncthreads();

    if (threadIdx.x < QG) {  // finalize
        int cl = cntless[threadIdx.x];
        if (cl >= 16) {
            TOP_DECL
            for (int i = 0; i < NN; i++) {
                unsigned int du = dist_du(qx, qy, qz, qsq, cand[i]);
                TOP_INSERT(du)
            }
            unsigned int Tt = t15;
            int fp = 0;
            for (int i = 0; i < NN && fp < KNNK; i++) {
                unsigned int du = dist_du(qx, qy, qz, qsq, cand[i]);
                if (du < Tt) sel[fp++][threadIdx.x] = (unsigned short)i;
            }
            for (int i = 0; i < NN && fp < KNNK; i++) {
                unsigned int du = dist_du(qx, qy, qz, qsq, cand[i]);
                if (du == Tt) sel[fp++][threadIdx.x] = (unsigned short)i;
            }
        } else {
            unsigned int T = Tq[threadIdx.x];
            int need = KNNK - cl;
            int tc = tiecnt[threadIdx.x];
            if (need > 0) {
                if (tc <= 16) {
                    for (int r = 0; r < need; r++) {
                        int best = 0x7fffffff, bj = 0;
                        for (int j = 0; j < tc; j++) {
                            int v = tieidx[j][threadIdx.x];
                            if (v < best) { best = v; bj = j; }
                        }
                        tieidx[bj][threadIdx.x] = 0xFFFF;
                        sel[cl + r][threadIdx.x] = (unsigned short)best;
                    }
                } else {
                    int em = 0;
                    for (int i = 0; i < NN && em < need; i++) {
                        unsigned int du = dist_du(qx, qy, qz, qsq, cand[i]);
                        if (du == T) { sel[cl + em][threadIdx.x] = (unsigned short)i; em++; }
                    }
                }
            }
        }
    }
    __syncthreads();

    if (lane < 32) {  // write-out
        int x = (int)sel[w][q32];
        knn_idx[(size_t)bq * KNNK + w] = x;
        int pos = atomicAdd(&revcnt[b * NN + x], 1);
        if (pos < REVCAP) rev[((size_t)(b * NN + x)) * REVCAP + pos] = q;
    }
}

// ---------------- spec: bf16 gathers, 4-way ILP, bf16 output (verified R23) ----------------
__global__ __launch_bounds__(128) void spec_kernel(const __bf16* __restrict__ fTB,
                                                   const int* __restrict__ knn_idx,
                                                   const int* __restrict__ revcnt,
                                                   const int* __restrict__ rev,
                                                   __bf16* __restrict__ specB) {
    __shared__ int ml[KNNK + REVCAP];
    __shared__ float wl[KNNK + REVCAP];
    __shared__ int s_cnt;
    __shared__ float s_dn;

    int bn = blockIdx.x;           // b*NN + n
    int b = bn >> 11;
    int tid = threadIdx.x;

    if (tid == 0) {
        int c = revcnt[bn];
        s_cnt = c < REVCAP ? c : REVCAP;
        float D = 0.5f * (float)(KNNK + c);
        s_dn = 1.0f / sqrtf(D + 1e-6f);
    }
    __syncthreads();
    int cnt = s_cnt;
    if (tid < KNNK) ml[tid] = knn_idx[(size_t)bn * KNNK + tid];
    if (tid < cnt) ml[KNNK + tid] = rev[(size_t)bn * REVCAP + tid];
    __syncthreads();
    int total = KNNK + cnt;
    if (tid < total) {
        int m = ml[tid];
        float D = 0.5f * (float)(KNNK + revcnt[b * NN + m]);
        wl[tid] = 0.5f * (1.0f / sqrtf(D + 1e-6f));
    }
    __syncthreads();

    const __bf16* base = fTB + (size_t)b * NN * CINC + tid;
    float acc0 = 0.0f, acc1 = 0.0f, acc2 = 0.0f, acc3 = 0.0f;
    int j = 0;
    for (; j + 4 <= total; j += 4) {
        float f0v = (float)base[(size_t)ml[j + 0] * CINC];
        float f1v = (float)base[(size_t)ml[j + 1] * CINC];
        float f2v = (float)base[(size_t)ml[j + 2] * CINC];
        float f3v = (float)base[(size_t)ml[j + 3] * CINC];
        acc0 = fmaf(wl[j + 0], f0v, acc0);
        acc1 = fmaf(wl[j + 1], f1v, acc1);
        acc2 = fmaf(wl[j + 2], f2v, acc2);
        acc3 = fmaf(wl[j + 3], f3v, acc3);
    }
    for (; j < total; j++)
        acc0 = fmaf(wl[j], (float)base[(size_t)ml[j] * CINC], acc0);
    float acc = (acc0 + acc1) + (acc2 + acc3);

    float f0 = (float)base[(size_t)(bn & (NN - 1)) * CINC];
    specB[(size_t)bn * CINC + tid] = (__bf16)(f0 - s_dn * acc);
}

// ---------------- fused GEMM1+GEMM2, BM=32 -> 512 blocks (2/CU) ----------------
// Only change vs verified R23 gemm12: tile rows 64->32 (phase-1 m-range and
// phase-2 n-range halved); fragment roles and MFMA mapping unchanged.
__global__ __launch_bounds__(256) void gemm12_fused(const __bf16* __restrict__ specB,
                                                    const __bf16* __restrict__ WspecB,
                                                    const float* __restrict__ bspec,
                                                    const float* __restrict__ gamma,
                                                    const float* __restrict__ beta,
                                                    const float* __restrict__ mean,
                                                    const float* __restrict__ var,
                                                    const __bf16* __restrict__ WcB,
                                                    const float* __restrict__ bc,
                                                    float* __restrict__ out) {
    __shared__ __bf16 g1s[32][COU + 8];    // 17 KB
    int b  = blockIdx.y;
    int n0 = blockIdx.x * 32;
    int w = threadIdx.x >> 6, lane = threadIdx.x & 63;
    int lr = lane & 15, lk = (lane >> 4) * 8;
    int rb = (lane >> 4) * 4;

    {   // phase 1: spec @ Wspec^T + bias/BN/GELU -> g1s (32 rows x 256 o)
        int o0 = w * 64;
        f32x4 acc[2][4] = {};
        const __bf16* As = specB + ((size_t)b * NN + n0 + lr) * CINC + lk;
        const __bf16* Bs = WspecB + (size_t)(o0 + lr) * CINC + lk;
#pragma unroll
        for (int kk = 0; kk < CINC; kk += 32) {
            bf16x8 a[2], bb[4];
#pragma unroll
            for (int m = 0; m < 2; m++)
                a[m] = *(const bf16x8*)(As + (size_t)(m * 16) * CINC + kk);
#pragma unroll
            for (int n = 0; n < 4; n++)
                bb[n] = *(const bf16x8*)(Bs + (size_t)(n * 16) * CINC + kk);
#pragma unroll
            for (int m = 0; m < 2; m++)
#pragma unroll
                for (int n = 0; n < 4; n++)
                    acc[m][n] = __builtin_amdgcn_mfma_f32_16x16x32_bf16(a[m], bb[n], acc[m][n], 0, 0, 0);
        }
#pragma unroll
        for (int n = 0; n < 4; n++) {
            int o = o0 + n * 16 + lr;
            float sc = 1.0f / sqrtf(var[o] + 1e-5f);
            float ga = gamma[o], be = beta[o], mu = mean[o], bs = bspec[o];
#pragma unroll
            for (int m = 0; m < 2; m++) {
#pragma unroll
                for (int j = 0; j < 4; j++) {
                    int nrow = m * 16 + rb + j;
                    float y = acc[m][n][j] + bs;
                    y = (y - mu) * sc;
                    y = y * ga + be;
                    float g = 0.5f * y * (1.0f + erff(y * 0.70710678118654752440f));
                    g1s[nrow][o] = (__bf16)g;
                }
            }
        }
    }
    __syncthreads();

    {   // phase 2: Wc @ g1^T + bias -> out (256 o x 32 n)
        int o0 = w * 64;
        f32x4 acc[4][2] = {};
        const __bf16* As = WcB + (size_t)(o0 + lr) * COU + lk;
#pragma unroll
        for (int kk = 0; kk < COU; kk += 32) {
            bf16x8 a[4], bb[2];
#pragma unroll
            for (int m = 0; m < 4; m++)
                a[m] = *(const bf16x8*)(As + (size_t)(m * 16) * COU + kk);
#pragma unroll
            for (int n = 0; n < 2; n++)
                bb[n] = *(const bf16x8*)(&g1s[n * 16 + lr][kk + lk]);
#pragma unroll
            for (int m = 0; m < 4; m++)
#pragma unroll
                for (int n = 0; n < 2; n++)
                    acc[m][n] = __builtin_amdgcn_mfma_f32_16x16x32_bf16(a[m], bb[n], acc[m][n], 0, 0, 0);
        }
#pragma unroll
        for (int m = 0; m < 4; m++) {
#pragma unroll
            for (int j = 0; j < 4; j++) {
                int o = o0 + m * 16 + rb + j;
                float bias = bc[o];
#pragma unroll
                for (int n = 0; n < 2; n++) {
                    int ncol = n0 + n * 16 + lr;
                    out[((size_t)b * COU + o) * NN + ncol] = acc[m][n][j] + bias;
                }
            }
        }
    }
}

extern "C" void kernel_launch(void* const* d_in, const int* in_sizes, int n_in,
                              void* d_out, int out_size, void* d_ws, size_t ws_size,
                              hipStream_t stream) {
    const float* xyz      = (const float*)d_in[0];
    const float* features = (const float*)d_in[1];
    const float* W_spec   = (const float*)d_in[2];
    const float* b_spec   = (const float*)d_in[3];
    const float* bn_gamma = (const float*)d_in[4];
    const float* bn_beta  = (const float*)d_in[5];
    const float* bn_mean  = (const float*)d_in[6];
    const float* bn_var   = (const float*)d_in[7];
    const float* W_low    = (const float*)d_in[8];
    const float* b_low    = (const float*)d_in[9];
    const float* W_high   = (const float*)d_in[10];
    const float* b_high   = (const float*)d_in[11];
    float* out = (float*)d_out;

    char* ws = (char*)d_ws;
    size_t off = 0;
    __bf16* fTB   = (__bf16*)(ws + off); off += (size_t)BB * NN * CINC * 2;      // 4 MB
    __bf16* specB = (__bf16*)(ws + off); off += (size_t)BB * NN * CINC * 2;      // 4 MB
    int*    idx   = (int*)(ws + off);    off += (size_t)BB * NN * KNNK * 4;      // 1 MB
    int*    rcnt  = (int*)(ws + off);    off += (size_t)BB * NN * 4;             // 64 KB
    int*    rev   = (int*)(ws + off);    off += (size_t)BB * NN * REVCAP * 4;    // 4 MB
    __bf16* WspecB= (__bf16*)(ws + off); off += (size_t)COU * CINC * 2;          // 64 KB
    __bf16* WcB   = (__bf16*)(ws + off); off += (size_t)COU * COU * 2;           // 128 KB
    float*  bc    = (float*)(ws + off);  off += (size_t)COU * 4;                 // 1 KB

    setup_kernel<<<dim3(2048 + 128), dim3(32, 8), 0, stream>>>(
        features, fTB, W_spec, W_low, W_high, b_low, b_high, WspecB, WcB, bc, rcnt);
    knn_fused_kernel<<<dim3(NN / QG, BB), dim3(1024), 0, stream>>>(xyz, idx, rcnt, rev);
    spec_kernel<<<dim3(BB * NN), dim3(128), 0, stream>>>(fTB, idx, rcnt, rev, specB);
    gemm12_fused<<<dim3(NN / 32, BB), dim3(256), 0, stream>>>(
        specB, WspecB, b_spec, bn_gamma, bn_beta, bn_mean, bn_var, WcB, bc, out);
}

// Round 26
// 90.814 us; speedup vs baseline: 1.0271x; 1.0271x over previous
//
#include <hip/hip_runtime.h>
#include <hip/hip_bf16.h>
#include <math.h>

#define BB   8
#define NN   2048
#define BN   (BB * NN)
#define CINC 128
#define COU  256
#define KNNK 16
#define REVCAP 64
#define QG   32            // queries per knn block

typedef __bf16 bf16x8 __attribute__((ext_vector_type(8)));
typedef float  f32x4  __attribute__((ext_vector_type(4)));

// Float median-of-3: single v_med3_f32 (finite values only; d is always finite).
#define FMED3(dst, a, bb_, c) asm("v_med3_f32 %0, %1, %2, %3" : "=v"(dst) : "v"(a), "v"(bb_), "v"(c))

#define INF32 (__builtin_inff())

// 16 sorted float regs t0<=..<=t15 (t8..t15 only used from the fold onward).
#define TOP_DECL \
    float t0=INF32,t1=INF32,t2=INF32,t3=INF32,t4=INF32,t5=INF32,t6=INF32,t7=INF32, \
          t8=INF32,t9=INF32,t10=INF32,t11=INF32,t12=INF32,t13=INF32,t14=INF32,t15=INF32;

// 16-deep insert (merge/fallback): 15 med3 + 1 min.
#define TOP_INSERT(u) {                     \
    FMED3(t15, t14, t15, (u));              \
    FMED3(t14, t13, t14, (u));              \
    FMED3(t13, t12, t13, (u));              \
    FMED3(t12, t11, t12, (u));              \
    FMED3(t11, t10, t11, (u));              \
    FMED3(t10, t9,  t10, (u));              \
    FMED3(t9,  t8,  t9,  (u));              \
    FMED3(t8,  t7,  t8,  (u));              \
    FMED3(t7,  t6,  t7,  (u));              \
    FMED3(t6,  t5,  t6,  (u));              \
    FMED3(t5,  t4,  t5,  (u));              \
    FMED3(t4,  t3,  t4,  (u));              \
    FMED3(t3,  t2,  t3,  (u));              \
    FMED3(t2,  t1,  t2,  (u));              \
    FMED3(t1,  t0,  t1,  (u));              \
    t0 = fminf(t0, (u));                    \
}

// 8-deep insert (hot scan): 7 med3 + 1 min.
#define TOP8_INSERT(u) {                    \
    FMED3(t7,  t6,  t7,  (u));              \
    FMED3(t6,  t5,  t6,  (u));              \
    FMED3(t5,  t4,  t5,  (u));              \
    FMED3(t4,  t3,  t4,  (u));              \
    FMED3(t3,  t2,  t3,  (u));              \
    FMED3(t2,  t1,  t2,  (u));              \
    FMED3(t1,  t0,  t1,  (u));              \
    t0 = fminf(t0, (u));                    \
}

// dist arithmetic: bit-identical to the verified R1-R25 formula, selection now
// on the raw float (strictly monotone with the old u32 ordered key; T > 0 so
// +-0 ambiguity cannot touch the threshold tie logic).
static __device__ __forceinline__ float dist_f(float qx, float qy, float qz,
                                               float qsq, float4 c) {
    float dot = fmaf(qz, c.z, fmaf(qy, c.y, __fmul_rn(qx, c.x)));
    return __fsub_rn(__fadd_rn(qsq, c.w), __fmul_rn(2.0f, dot));
}

// ---------------- setup: transpose + prep weights + zero rcnt (verified R23) ----------------
__global__ __launch_bounds__(256) void setup_kernel(const float* __restrict__ feat,
                                                    __bf16* __restrict__ fTB,
                                                    const float* __restrict__ Wspec,
                                                    const float* __restrict__ Wlow,
                                                    const float* __restrict__ Whigh,
                                                    const float* __restrict__ blow,
                                                    const float* __restrict__ bhigh,
                                                    __bf16* __restrict__ WspecB,
                                                    __bf16* __restrict__ WcB,
                                                    float* __restrict__ bc,
                                                    int* __restrict__ rcnt) {
    __shared__ float t[32][33];
    int bid = blockIdx.x;
    int tx = threadIdx.x, ty = threadIdx.y;  // (32,8)
    if (bid < 2048) {
        int b  = bid >> 8;
        int r  = bid & 255;
        int n0 = (r & 63) * 32;
        int c0 = (r >> 6) * 32;
#pragma unroll
        for (int i = 0; i < 4; i++)
            t[ty + i * 8][tx] = feat[((size_t)b * CINC + c0 + ty + i * 8) * NN + n0 + tx];
        __syncthreads();
#pragma unroll
        for (int i = 0; i < 4; i++)
            fTB[((size_t)b * NN + n0 + ty + i * 8) * CINC + c0 + tx] = (__bf16)t[tx][ty + i * 8];
    } else {
        int r = bid - 2048;                  // 0..127
        int i = r * 256 + ty * 32 + tx;
        if (i < COU * CINC) WspecB[i] = (__bf16)Wspec[i];
        if (i < 128 * COU) {
            WcB[i] = (__bf16)Wlow[i];
            WcB[128 * COU + i] = (__bf16)Whigh[i];
        }
        if (i < 128) { bc[i] = blow[i]; bc[128 + i] = bhigh[i]; }
        rcnt[r * 128 + (ty * 32 + tx) % 128] = 0;
    }
}

// ---------------- KNN fused v7: float med3 selection (structure = verified v6) ----------------
__global__ __launch_bounds__(1024, 8) void knn_fused_kernel(const float* __restrict__ xyz,
                                                            int* __restrict__ knn_idx,
                                                            int* __restrict__ revcnt,
                                                            int* __restrict__ rev) {
    __shared__ float4 cand[NN];                     // 32 KB
    __shared__ float mbuf[8][KNNK][QG];             // 16 KB
    __shared__ float Tq[QG];
    __shared__ int cntless[QG];
    __shared__ int tiecnt[QG];
    __shared__ unsigned short tieidx[16][QG];
    __shared__ unsigned short sel[KNNK][QG];

    int b = blockIdx.y;
    int lane = threadIdx.x & 63;
    int w = threadIdx.x >> 6;
    int q32 = lane & 31;
    int qh = lane >> 5;
    int q = blockIdx.x * QG + q32;
    int bq = b * NN + q;

    const float* xb = xyz + (size_t)b * 3 * NN;
    for (int t = threadIdx.x; t < NN; t += 1024) {
        float x = xb[t], y = xb[NN + t], z = xb[2 * NN + t];
        float sq = __fadd_rn(__fadd_rn(__fmul_rn(x, x), __fmul_rn(y, y)), __fmul_rn(z, z));
        cand[t] = make_float4(x, y, z, sq);
    }
    if (threadIdx.x < QG) { cntless[threadIdx.x] = 0; tiecnt[threadIdx.x] = 0; }
    __syncthreads();

    float qx = xb[q], qy = xb[NN + q], qz = xb[2 * NN + q];
    float qsq = __fadd_rn(__fadd_rn(__fmul_rn(qx, qx), __fmul_rn(qy, qy)), __fmul_rn(qz, qz));

    int segbase = w * 128 + qh * 64;

    TOP_DECL
    for (int i = 0; i < 64; i += 4) {   // phase A: 8-deep scan
        float4 c0 = cand[segbase + i + 0];
        float4 c1 = cand[segbase + i + 1];
        float4 c2 = cand[segbase + i + 2];
        float4 c3 = cand[segbase + i + 3];
        float d0 = dist_f(qx, qy, qz, qsq, c0);
        float d1 = dist_f(qx, qy, qz, qsq, c1);
        float d2 = dist_f(qx, qy, qz, qsq, c2);
        float d3 = dist_f(qx, qy, qz, qsq, c3);
        TOP8_INSERT(d0)
        TOP8_INSERT(d1)
        TOP8_INSERT(d2)
        TOP8_INSERT(d3)
    }

    {   // intra-wave fold
        float s0 = __shfl_xor(t0, 32), s1 = __shfl_xor(t1, 32);
        float s2 = __shfl_xor(t2, 32), s3 = __shfl_xor(t3, 32);
        float s4 = __shfl_xor(t4, 32), s5 = __shfl_xor(t5, 32);
        float s6 = __shfl_xor(t6, 32), s7 = __shfl_xor(t7, 32);
        TOP_INSERT(s0) TOP_INSERT(s1) TOP_INSERT(s2) TOP_INSERT(s3)
        TOP_INSERT(s4) TOP_INSERT(s5) TOP_INSERT(s6) TOP_INSERT(s7)
    }

    for (int s = 8; s >= 1; s >>= 1) {  // tree merge
        if (w >= s && w < 2 * s && lane < 32) {
            int j = w - s;
            mbuf[j][0][q32] = t0;   mbuf[j][1][q32] = t1;
            mbuf[j][2][q32] = t2;   mbuf[j][3][q32] = t3;
            mbuf[j][4][q32] = t4;   mbuf[j][5][q32] = t5;
            mbuf[j][6][q32] = t6;   mbuf[j][7][q32] = t7;
            mbuf[j][8][q32] = t8;   mbuf[j][9][q32] = t9;
            mbuf[j][10][q32] = t10; mbuf[j][11][q32] = t11;
            mbuf[j][12][q32] = t12; mbuf[j][13][q32] = t13;
            mbuf[j][14][q32] = t14; mbuf[j][15][q32] = t15;
        }
        __syncthreads();
        if (w < s) {
#pragma unroll
            for (int k = 0; k < KNNK; k++) {
                float u = mbuf[w][k][q32];
                TOP_INSERT(u)
            }
        }
        __syncthreads();
    }
    if (w == 0 && lane < 32) Tq[q32] = t15;
    __syncthreads();

    {   // emission
        float T = Tq[q32];
        for (int i = 0; i < 64; i++) {
            float4 c = cand[segbase + i];
            float du = dist_f(qx, qy, qz, qsq, c);
            if (du < T) {
                int slot = atomicAdd(&cntless[q32], 1);
                if (slot < 16) sel[slot][q32] = (unsigned short)(segbase + i);
            } else if (du == T) {
                int t = atomicAdd(&tiecnt[q32], 1);
                if (t < 16) tieidx[t][q32] = (unsigned short)(segbase + i);
            }
        }
    }
    __syncthreads();

    if (threadIdx.x < QG) {  // finalize
        int cl = cntless[threadIdx.x];
        if (cl >= 16) {
            TOP_DECL
            for (int i = 0; i < NN; i++) {
                float du = dist_f(qx, qy, qz, qsq, cand[i]);
                TOP_INSERT(du)
            }
            float Tt = t15;
            int fp = 0;
            for (int i = 0; i < NN && fp < KNNK; i++) {
                float du = dist_f(qx, qy, qz, qsq, cand[i]);
                if (du < Tt) sel[fp++][threadIdx.x] = (unsigned short)i;
            }
            for (int i = 0; i < NN && fp < KNNK; i++) {
                float du = dist_f(qx, qy, qz, qsq, cand[i]);
                if (du == Tt) sel[fp++][threadIdx.x] = (unsigned short)i;
            }
        } else {
            float T = Tq[threadIdx.x];
            int need = KNNK - cl;
            int tc = tiecnt[threadIdx.x];
            if (need > 0) {
                if (tc <= 16) {
                    for (int r = 0; r < need; r++) {
                        int best = 0x7fffffff, bj = 0;
                        for (int j = 0; j < tc; j++) {
                            int v = tieidx[j][threadIdx.x];
                            if (v < best) { best = v; bj = j; }
                        }
                        tieidx[bj][threadIdx.x] = 0xFFFF;
                        sel[cl + r][threadIdx.x] = (unsigned short)best;
                    }
                } else {
                    int em = 0;
                    for (int i = 0; i < NN && em < need; i++) {
                        float du = dist_f(qx, qy, qz, qsq, cand[i]);
                        if (du == T) { sel[cl + em][threadIdx.x] = (unsigned short)i; em++; }
                    }
                }
            }
        }
    }
    __syncthreads();

    if (lane < 32) {  // write-out
        int x = (int)sel[w][q32];
        knn_idx[(size_t)bq * KNNK + w] = x;
        int pos = atomicAdd(&revcnt[b * NN + x], 1);
        if (pos < REVCAP) rev[((size_t)(b * NN + x)) * REVCAP + pos] = q;
    }
}

// ---------------- spec: bf16 gathers, 4-way ILP, bf16 output (verified R23) ----------------
__global__ __launch_bounds__(128) void spec_kernel(const __bf16* __restrict__ fTB,
                                                   const int* __restrict__ knn_idx,
                                                   const int* __restrict__ revcnt,
                                                   const int* __restrict__ rev,
                                                   __bf16* __restrict__ specB) {
    __shared__ int ml[KNNK + REVCAP];
    __shared__ float wl[KNNK + REVCAP];
    __shared__ int s_cnt;
    __shared__ float s_dn;

    int bn = blockIdx.x;           // b*NN + n
    int b = bn >> 11;
    int tid = threadIdx.x;

    if (tid == 0) {
        int c = revcnt[bn];
        s_cnt = c < REVCAP ? c : REVCAP;
        float D = 0.5f * (float)(KNNK + c);
        s_dn = 1.0f / sqrtf(D + 1e-6f);
    }
    __syncthreads();
    int cnt = s_cnt;
    if (tid < KNNK) ml[tid] = knn_idx[(size_t)bn * KNNK + tid];
    if (tid < cnt) ml[KNNK + tid] = rev[(size_t)bn * REVCAP + tid];
    __syncthreads();
    int total = KNNK + cnt;
    if (tid < total) {
        int m = ml[tid];
        float D = 0.5f * (float)(KNNK + revcnt[b * NN + m]);
        wl[tid] = 0.5f * (1.0f / sqrtf(D + 1e-6f));
    }
    __syncthreads();

    const __bf16* base = fTB + (size_t)b * NN * CINC + tid;
    float acc0 = 0.0f, acc1 = 0.0f, acc2 = 0.0f, acc3 = 0.0f;
    int j = 0;
    for (; j + 4 <= total; j += 4) {
        float f0v = (float)base[(size_t)ml[j + 0] * CINC];
        float f1v = (float)base[(size_t)ml[j + 1] * CINC];
        float f2v = (float)base[(size_t)ml[j + 2] * CINC];
        float f3v = (float)base[(size_t)ml[j + 3] * CINC];
        acc0 = fmaf(wl[j + 0], f0v, acc0);
        acc1 = fmaf(wl[j + 1], f1v, acc1);
        acc2 = fmaf(wl[j + 2], f2v, acc2);
        acc3 = fmaf(wl[j + 3], f3v, acc3);
    }
    for (; j < total; j++)
        acc0 = fmaf(wl[j], (float)base[(size_t)ml[j] * CINC], acc0);
    float acc = (acc0 + acc1) + (acc2 + acc3);

    float f0 = (float)base[(size_t)(bn & (NN - 1)) * CINC];
    specB[(size_t)bn * CINC + tid] = (__bf16)(f0 - s_dn * acc);
}

// ---------------- fused GEMM1+GEMM2 via LDS g1 tile (verified R23, BM=64) ----------------
__global__ __launch_bounds__(256) void gemm12_fused(const __bf16* __restrict__ specB,
                                                    const __bf16* __restrict__ WspecB,
                                                    const float* __restrict__ bspec,
                                                    const float* __restrict__ gamma,
                                                    const float* __restrict__ beta,
                                                    const float* __restrict__ mean,
                                                    const float* __restrict__ var,
                                                    const __bf16* __restrict__ WcB,
                                                    const float* __restrict__ bc,
                                                    float* __restrict__ out) {
    __shared__ __bf16 g1s[64][COU + 8];
    int b  = blockIdx.y;
    int n0 = blockIdx.x * 64;
    int w = threadIdx.x >> 6, lane = threadIdx.x & 63;
    int lr = lane & 15, lk = (lane >> 4) * 8;
    int rb = (lane >> 4) * 4;

    {   // phase 1: spec @ Wspec^T + bias/BN/GELU -> g1s
        int o0 = w * 64;
        f32x4 acc[4][4] = {};
        const __bf16* As = specB + ((size_t)b * NN + n0 + lr) * CINC + lk;
        const __bf16* Bs = WspecB + (size_t)(o0 + lr) * CINC + lk;
#pragma unroll
        for (int kk = 0; kk < CINC; kk += 32) {
            bf16x8 a[4], bb[4];
#pragma unroll
            for (int m = 0; m < 4; m++)
                a[m] = *(const bf16x8*)(As + (size_t)(m * 16) * CINC + kk);
#pragma unroll
            for (int n = 0; n < 4; n++)
                bb[n] = *(const bf16x8*)(Bs + (size_t)(n * 16) * CINC + kk);
#pragma unroll
            for (int m = 0; m < 4; m++)
#pragma unroll
                for (int n = 0; n < 4; n++)
                    acc[m][n] = __builtin_amdgcn_mfma_f32_16x16x32_bf16(a[m], bb[n], acc[m][n], 0, 0, 0);
        }
#pragma unroll
        for (int n = 0; n < 4; n++) {
            int o = o0 + n * 16 + lr;
            float sc = 1.0f / sqrtf(var[o] + 1e-5f);
            float ga = gamma[o], be = beta[o], mu = mean[o], bs = bspec[o];
#pragma unroll
            for (int m = 0; m < 4; m++) {
#pragma unroll
                for (int j = 0; j < 4; j++) {
                    int nrow = m * 16 + rb + j;
                    float y = acc[m][n][j] + bs;
                    y = (y - mu) * sc;
                    y = y * ga + be;
                    float g = 0.5f * y * (1.0f + erff(y * 0.70710678118654752440f));
                    g1s[nrow][o] = (__bf16)g;
                }
            }
        }
    }
    __syncthreads();

    {   // phase 2: Wc @ g1^T + bias -> out
        int o0 = w * 64;
        f32x4 acc[4][4] = {};
        const __bf16* As = WcB + (size_t)(o0 + lr) * COU + lk;
#pragma unroll
        for (int kk = 0; kk < COU; kk += 32) {
            bf16x8 a[4], bb[4];
#pragma unroll
            for (int m = 0; m < 4; m++)
                a[m] = *(const bf16x8*)(As + (size_t)(m * 16) * COU + kk);
#pragma unroll
            for (int n = 0; n < 4; n++)
                bb[n] = *(const bf16x8*)(&g1s[n * 16 + lr][kk + lk]);
#pragma unroll
            for (int m = 0; m < 4; m++)
#pragma unroll
                for (int n = 0; n < 4; n++)
                    acc[m][n] = __builtin_amdgcn_mfma_f32_16x16x32_bf16(a[m], bb[n], acc[m][n], 0, 0, 0);
        }
#pragma unroll
        for (int m = 0; m < 4; m++) {
#pragma unroll
            for (int j = 0; j < 4; j++) {
                int o = o0 + m * 16 + rb + j;
                float bias = bc[o];
#pragma unroll
                for (int n = 0; n < 4; n++) {
                    int ncol = n0 + n * 16 + lr;
                    out[((size_t)b * COU + o) * NN + ncol] = acc[m][n][j] + bias;
                }
            }
        }
    }
}

extern "C" void kernel_launch(void* const* d_in, const int* in_sizes, int n_in,
                              void* d_out, int out_size, void* d_ws, size_t ws_size,
                              hipStream_t stream) {
    const float* xyz      = (const float*)d_in[0];
    const float* features = (const float*)d_in[1];
    const float* W_spec   = (const float*)d_in[2];
    const float* b_spec   = (const float*)d_in[3];
    const float* bn_gamma = (const float*)d_in[4];
    const float* bn_beta  = (const float*)d_in[5];
    const float* bn_mean  = (const float*)d_in[6];
    const float* bn_var   = (const float*)d_in[7];
    const float* W_low    = (const float*)d_in[8];
    const float* b_low    = (const float*)d_in[9];
    const float* W_high   = (const float*)d_in[10];
    const float* b_high   = (const float*)d_in[11];
    float* out = (float*)d_out;

    char* ws = (char*)d_ws;
    size_t off = 0;
    __bf16* fTB   = (__bf16*)(ws + off); off += (size_t)BB * NN * CINC * 2;      // 4 MB
    __bf16* specB = (__bf16*)(ws + off); off += (size_t)BB * NN * CINC * 2;      // 4 MB
    int*    idx   = (int*)(ws + off);    off += (size_t)BB * NN * KNNK * 4;      // 1 MB
    int*    rcnt  = (int*)(ws + off);    off += (size_t)BB * NN * 4;             // 64 KB
    int*    rev   = (int*)(ws + off);    off += (size_t)BB * NN * REVCAP * 4;    // 4 MB
    __bf16* WspecB= (__bf16*)(ws + off); off += (size_t)COU * CINC * 2;          // 64 KB
    __bf16* WcB   = (__bf16*)(ws + off); off += (size_t)COU * COU * 2;           // 128 KB
    float*  bc    = (float*)(ws + off);  off += (size_t)COU * 4;                 // 1 KB

    setup_kernel<<<dim3(2048 + 128), dim3(32, 8), 0, stream>>>(
        features, fTB, W_spec, W_low, W_high, b_low, b_high, WspecB, WcB, bc, rcnt);
    knn_fused_kernel<<<dim3(NN / QG, BB), dim3(1024), 0, stream>>>(xyz, idx, rcnt, rev);
    spec_kernel<<<dim3(BB * NN), dim3(128), 0, stream>>>(fTB, idx, rcnt, rev, specB);
    gemm12_fused<<<dim3(NN / 64, BB), dim3(256), 0, stream>>>(
        specB, WspecB, b_spec, bn_gamma, bn_beta, bn_mean, bn_var, WcB, bc, out);
}

// Round 27
// 89.114 us; speedup vs baseline: 1.0467x; 1.0191x over previous
//
#include <hip/hip_runtime.h>
#include <hip/hip_bf16.h>
#include <math.h>

#define BB   8
#define NN   2048
#define BN   (BB * NN)
#define CINC 128
#define COU  256
#define KNNK 16
#define REVCAP 64
#define QG   32            // queries per knn block

typedef __bf16 bf16x8 __attribute__((ext_vector_type(8)));
typedef float  f32x4  __attribute__((ext_vector_type(4)));

// Float median-of-3: single v_med3_f32 (finite values only; d is always finite).
#define FMED3(dst, a, bb_, c) asm("v_med3_f32 %0, %1, %2, %3" : "=v"(dst) : "v"(a), "v"(bb_), "v"(c))

#define INF32 (__builtin_inff())

// 16 sorted float regs t0<=..<=t15 (t8..t15 only used from the fold onward).
#define TOP_DECL \
    float t0=INF32,t1=INF32,t2=INF32,t3=INF32,t4=INF32,t5=INF32,t6=INF32,t7=INF32, \
          t8=INF32,t9=INF32,t10=INF32,t11=INF32,t12=INF32,t13=INF32,t14=INF32,t15=INF32;

// 16-deep insert (merge/fallback): 15 med3 + 1 min.
#define TOP_INSERT(u) {                     \
    FMED3(t15, t14, t15, (u));              \
    FMED3(t14, t13, t14, (u));              \
    FMED3(t13, t12, t13, (u));              \
    FMED3(t12, t11, t12, (u));              \
    FMED3(t11, t10, t11, (u));              \
    FMED3(t10, t9,  t10, (u));              \
    FMED3(t9,  t8,  t9,  (u));              \
    FMED3(t8,  t7,  t8,  (u));              \
    FMED3(t7,  t6,  t7,  (u));              \
    FMED3(t6,  t5,  t6,  (u));              \
    FMED3(t5,  t4,  t5,  (u));              \
    FMED3(t4,  t3,  t4,  (u));              \
    FMED3(t3,  t2,  t3,  (u));              \
    FMED3(t2,  t1,  t2,  (u));              \
    FMED3(t1,  t0,  t1,  (u));              \
    t0 = fminf(t0, (u));                    \
}

// 8-deep insert (hot scan): 7 med3 + 1 min.
#define TOP8_INSERT(u) {                    \
    FMED3(t7,  t6,  t7,  (u));              \
    FMED3(t6,  t5,  t6,  (u));              \
    FMED3(t5,  t4,  t5,  (u));              \
    FMED3(t4,  t3,  t4,  (u));              \
    FMED3(t3,  t2,  t3,  (u));              \
    FMED3(t2,  t1,  t2,  (u));              \
    FMED3(t1,  t0,  t1,  (u));              \
    t0 = fminf(t0, (u));                    \
}

// dist arithmetic: bit-identical to the verified R1-R26 formula.
static __device__ __forceinline__ float dist_f(float qx, float qy, float qz,
                                               float qsq, float4 c) {
    float dot = fmaf(qz, c.z, fmaf(qy, c.y, __fmul_rn(qx, c.x)));
    return __fsub_rn(__fadd_rn(qsq, c.w), __fmul_rn(2.0f, dot));
}

// ---------------- setup: transpose + prep weights + zero rcnt (verified R23) ----------------
__global__ __launch_bounds__(256) void setup_kernel(const float* __restrict__ feat,
                                                    __bf16* __restrict__ fTB,
                                                    const float* __restrict__ Wspec,
                                                    const float* __restrict__ Wlow,
                                                    const float* __restrict__ Whigh,
                                                    const float* __restrict__ blow,
                                                    const float* __restrict__ bhigh,
                                                    __bf16* __restrict__ WspecB,
                                                    __bf16* __restrict__ WcB,
                                                    float* __restrict__ bc,
                                                    int* __restrict__ rcnt) {
    __shared__ float t[32][33];
    int bid = blockIdx.x;
    int tx = threadIdx.x, ty = threadIdx.y;  // (32,8)
    if (bid < 2048) {
        int b  = bid >> 8;
        int r  = bid & 255;
        int n0 = (r & 63) * 32;
        int c0 = (r >> 6) * 32;
#pragma unroll
        for (int i = 0; i < 4; i++)
            t[ty + i * 8][tx] = feat[((size_t)b * CINC + c0 + ty + i * 8) * NN + n0 + tx];
        __syncthreads();
#pragma unroll
        for (int i = 0; i < 4; i++)
            fTB[((size_t)b * NN + n0 + ty + i * 8) * CINC + c0 + tx] = (__bf16)t[tx][ty + i * 8];
    } else {
        int r = bid - 2048;                  // 0..127
        int i = r * 256 + ty * 32 + tx;
        if (i < COU * CINC) WspecB[i] = (__bf16)Wspec[i];
        if (i < 128 * COU) {
            WcB[i] = (__bf16)Wlow[i];
            WcB[128 * COU + i] = (__bf16)Whigh[i];
        }
        if (i < 128) { bc[i] = blow[i]; bc[128 + i] = bhigh[i]; }
        rcnt[r * 128 + (ty * 32 + tx) % 128] = 0;
    }
}

// ---------------- KNN fused v8: v7 + fully unrolled scan loops ----------------
__global__ __launch_bounds__(1024, 8) void knn_fused_kernel(const float* __restrict__ xyz,
                                                            int* __restrict__ knn_idx,
                                                            int* __restrict__ revcnt,
                                                            int* __restrict__ rev) {
    __shared__ float4 cand[NN];                     // 32 KB
    __shared__ float mbuf[8][KNNK][QG];             // 16 KB
    __shared__ float Tq[QG];
    __shared__ int cntless[QG];
    __shared__ int tiecnt[QG];
    __shared__ unsigned short tieidx[16][QG];
    __shared__ unsigned short sel[KNNK][QG];

    int b = blockIdx.y;
    int lane = threadIdx.x & 63;
    int w = threadIdx.x >> 6;
    int q32 = lane & 31;
    int qh = lane >> 5;
    int q = blockIdx.x * QG + q32;
    int bq = b * NN + q;

    const float* xb = xyz + (size_t)b * 3 * NN;
#pragma unroll
    for (int t0i = 0; t0i < 2; t0i++) {
        int t = threadIdx.x + t0i * 1024;
        float x = xb[t], y = xb[NN + t], z = xb[2 * NN + t];
        float sq = __fadd_rn(__fadd_rn(__fmul_rn(x, x), __fmul_rn(y, y)), __fmul_rn(z, z));
        cand[t] = make_float4(x, y, z, sq);
    }
    if (threadIdx.x < QG) { cntless[threadIdx.x] = 0; tiecnt[threadIdx.x] = 0; }
    __syncthreads();

    float qx = xb[q], qy = xb[NN + q], qz = xb[2 * NN + q];
    float qsq = __fadd_rn(__fadd_rn(__fmul_rn(qx, qx), __fmul_rn(qy, qy)), __fmul_rn(qz, qz));

    int segbase = w * 128 + qh * 64;

    TOP_DECL
#pragma unroll
    for (int i = 0; i < 64; i += 4) {   // phase A: 8-deep scan (fully unrolled)
        float4 c0 = cand[segbase + i + 0];
        float4 c1 = cand[segbase + i + 1];
        float4 c2 = cand[segbase + i + 2];
        float4 c3 = cand[segbase + i + 3];
        float d0 = dist_f(qx, qy, qz, qsq, c0);
        float d1 = dist_f(qx, qy, qz, qsq, c1);
        float d2 = dist_f(qx, qy, qz, qsq, c2);
        float d3 = dist_f(qx, qy, qz, qsq, c3);
        TOP8_INSERT(d0)
        TOP8_INSERT(d1)
        TOP8_INSERT(d2)
        TOP8_INSERT(d3)
    }

    {   // intra-wave fold
        float s0 = __shfl_xor(t0, 32), s1 = __shfl_xor(t1, 32);
        float s2 = __shfl_xor(t2, 32), s3 = __shfl_xor(t3, 32);
        float s4 = __shfl_xor(t4, 32), s5 = __shfl_xor(t5, 32);
        float s6 = __shfl_xor(t6, 32), s7 = __shfl_xor(t7, 32);
        TOP_INSERT(s0) TOP_INSERT(s1) TOP_INSERT(s2) TOP_INSERT(s3)
        TOP_INSERT(s4) TOP_INSERT(s5) TOP_INSERT(s6) TOP_INSERT(s7)
    }

    for (int s = 8; s >= 1; s >>= 1) {  // tree merge
        if (w >= s && w < 2 * s && lane < 32) {
            int j = w - s;
            mbuf[j][0][q32] = t0;   mbuf[j][1][q32] = t1;
            mbuf[j][2][q32] = t2;   mbuf[j][3][q32] = t3;
            mbuf[j][4][q32] = t4;   mbuf[j][5][q32] = t5;
            mbuf[j][6][q32] = t6;   mbuf[j][7][q32] = t7;
            mbuf[j][8][q32] = t8;   mbuf[j][9][q32] = t9;
            mbuf[j][10][q32] = t10; mbuf[j][11][q32] = t11;
            mbuf[j][12][q32] = t12; mbuf[j][13][q32] = t13;
            mbuf[j][14][q32] = t14; mbuf[j][15][q32] = t15;
        }
        __syncthreads();
        if (w < s) {
#pragma unroll
            for (int k = 0; k < KNNK; k++) {
                float u = mbuf[w][k][q32];
                TOP_INSERT(u)
            }
        }
        __syncthreads();
    }
    if (w == 0 && lane < 32) Tq[q32] = t15;
    __syncthreads();

    {   // emission (fully unrolled: immediate LDS offsets, batched reads)
        float T = Tq[q32];
#pragma unroll
        for (int i = 0; i < 64; i++) {
            float4 c = cand[segbase + i];
            float du = dist_f(qx, qy, qz, qsq, c);
            if (du < T) {
                int slot = atomicAdd(&cntless[q32], 1);
                if (slot < 16) sel[slot][q32] = (unsigned short)(segbase + i);
            } else if (du == T) {
                int t = atomicAdd(&tiecnt[q32], 1);
                if (t < 16) tieidx[t][q32] = (unsigned short)(segbase + i);
            }
        }
    }
    __syncthreads();

    if (threadIdx.x < QG) {  // finalize
        int cl = cntless[threadIdx.x];
        if (cl >= 16) {
            TOP_DECL
            for (int i = 0; i < NN; i++) {
                float du = dist_f(qx, qy, qz, qsq, cand[i]);
                TOP_INSERT(du)
            }
            float Tt = t15;
            int fp = 0;
            for (int i = 0; i < NN && fp < KNNK; i++) {
                float du = dist_f(qx, qy, qz, qsq, cand[i]);
                if (du < Tt) sel[fp++][threadIdx.x] = (unsigned short)i;
            }
            for (int i = 0; i < NN && fp < KNNK; i++) {
                float du = dist_f(qx, qy, qz, qsq, cand[i]);
                if (du == Tt) sel[fp++][threadIdx.x] = (unsigned short)i;
            }
        } else {
            float T = Tq[threadIdx.x];
            int need = KNNK - cl;
            int tc = tiecnt[threadIdx.x];
            if (need > 0) {
                if (tc <= 16) {
                    for (int r = 0; r < need; r++) {
                        int best = 0x7fffffff, bj = 0;
                        for (int j = 0; j < tc; j++) {
                            int v = tieidx[j][threadIdx.x];
                            if (v < best) { best = v; bj = j; }
                        }
                        tieidx[bj][threadIdx.x] = 0xFFFF;
                        sel[cl + r][threadIdx.x] = (unsigned short)best;
                    }
                } else {
                    int em = 0;
                    for (int i = 0; i < NN && em < need; i++) {
                        float du = dist_f(qx, qy, qz, qsq, cand[i]);
                        if (du == T) { sel[cl + em][threadIdx.x] = (unsigned short)i; em++; }
                    }
                }
            }
        }
    }
    __syncthreads();

    if (lane < 32) {  // write-out
        int x = (int)sel[w][q32];
        knn_idx[(size_t)bq * KNNK + w] = x;
        int pos = atomicAdd(&revcnt[b * NN + x], 1);
        if (pos < REVCAP) rev[((size_t)(b * NN + x)) * REVCAP + pos] = q;
    }
}

// ---------------- spec: bf16 gathers, 4-way ILP, bf16 output (verified R23) ----------------
__global__ __launch_bounds__(128) void spec_kernel(const __bf16* __restrict__ fTB,
                                                   const int* __restrict__ knn_idx,
                                                   const int* __restrict__ revcnt,
                                                   const int* __restrict__ rev,
                                                   __bf16* __restrict__ specB) {
    __shared__ int ml[KNNK + REVCAP];
    __shared__ float wl[KNNK + REVCAP];
    __shared__ int s_cnt;
    __shared__ float s_dn;

    int bn = blockIdx.x;           // b*NN + n
    int b = bn >> 11;
    int tid = threadIdx.x;

    if (tid == 0) {
        int c = revcnt[bn];
        s_cnt = c < REVCAP ? c : REVCAP;
        float D = 0.5f * (float)(KNNK + c);
        s_dn = 1.0f / sqrtf(D + 1e-6f);
    }
    __syncthreads();
    int cnt = s_cnt;
    if (tid < KNNK) ml[tid] = knn_idx[(size_t)bn * KNNK + tid];
    if (tid < cnt) ml[KNNK + tid] = rev[(size_t)bn * REVCAP + tid];
    __syncthreads();
    int total = KNNK + cnt;
    if (tid < total) {
        int m = ml[tid];
        float D = 0.5f * (float)(KNNK + revcnt[b * NN + m]);
        wl[tid] = 0.5f * (1.0f / sqrtf(D + 1e-6f));
    }
    __syncthreads();

    const __bf16* base = fTB + (size_t)b * NN * CINC + tid;
    float acc0 = 0.0f, acc1 = 0.0f, acc2 = 0.0f, acc3 = 0.0f;
    int j = 0;
    for (; j + 4 <= total; j += 4) {
        float f0v = (float)base[(size_t)ml[j + 0] * CINC];
        float f1v = (float)base[(size_t)ml[j + 1] * CINC];
        float f2v = (float)base[(size_t)ml[j + 2] * CINC];
        float f3v = (float)base[(size_t)ml[j + 3] * CINC];
        acc0 = fmaf(wl[j + 0], f0v, acc0);
        acc1 = fmaf(wl[j + 1], f1v, acc1);
        acc2 = fmaf(wl[j + 2], f2v, acc2);
        acc3 = fmaf(wl[j + 3], f3v, acc3);
    }
    for (; j < total; j++)
        acc0 = fmaf(wl[j], (float)base[(size_t)ml[j] * CINC], acc0);
    float acc = (acc0 + acc1) + (acc2 + acc3);

    float f0 = (float)base[(size_t)(bn & (NN - 1)) * CINC];
    specB[(size_t)bn * CINC + tid] = (__bf16)(f0 - s_dn * acc);
}

// ---------------- fused GEMM1+GEMM2 via LDS g1 tile (verified R23, BM=64) ----------------
__global__ __launch_bounds__(256) void gemm12_fused(const __bf16* __restrict__ specB,
                                                    const __bf16* __restrict__ WspecB,
                                                    const float* __restrict__ bspec,
                                                    const float* __restrict__ gamma,
                                                    const float* __restrict__ beta,
                                                    const float* __restrict__ mean,
                                                    const float* __restrict__ var,
                                                    const __bf16* __restrict__ WcB,
                                                    const float* __restrict__ bc,
                                                    float* __restrict__ out) {
    __shared__ __bf16 g1s[64][COU + 8];
    int b  = blockIdx.y;
    int n0 = blockIdx.x * 64;
    int w = threadIdx.x >> 6, lane = threadIdx.x & 63;
    int lr = lane & 15, lk = (lane >> 4) * 8;
    int rb = (lane >> 4) * 4;

    {   // phase 1: spec @ Wspec^T + bias/BN/GELU -> g1s
        int o0 = w * 64;
        f32x4 acc[4][4] = {};
        const __bf16* As = specB + ((size_t)b * NN + n0 + lr) * CINC + lk;
        const __bf16* Bs = WspecB + (size_t)(o0 + lr) * CINC + lk;
#pragma unroll
        for (int kk = 0; kk < CINC; kk += 32) {
            bf16x8 a[4], bb[4];
#pragma unroll
            for (int m = 0; m < 4; m++)
                a[m] = *(const bf16x8*)(As + (size_t)(m * 16) * CINC + kk);
#pragma unroll
            for (int n = 0; n < 4; n++)
                bb[n] = *(const bf16x8*)(Bs + (size_t)(n * 16) * CINC + kk);
#pragma unroll
            for (int m = 0; m < 4; m++)
#pragma unroll
                for (int n = 0; n < 4; n++)
                    acc[m][n] = __builtin_amdgcn_mfma_f32_16x16x32_bf16(a[m], bb[n], acc[m][n], 0, 0, 0);
        }
#pragma unroll
        for (int n = 0; n < 4; n++) {
            int o = o0 + n * 16 + lr;
            float sc = 1.0f / sqrtf(var[o] + 1e-5f);
            float ga = gamma[o], be = beta[o], mu = mean[o], bs = bspec[o];
#pragma unroll
            for (int m = 0; m < 4; m++) {
#pragma unroll
                for (int j = 0; j < 4; j++) {
                    int nrow = m * 16 + rb + j;
                    float y = acc[m][n][j] + bs;
                    y = (y - mu) * sc;
                    y = y * ga + be;
                    float g = 0.5f * y * (1.0f + erff(y * 0.70710678118654752440f));
                    g1s[nrow][o] = (__bf16)g;
                }
            }
        }
    }
    __syncthreads();

    {   // phase 2: Wc @ g1^T + bias -> out
        int o0 = w * 64;
        f32x4 acc[4][4] = {};
        const __bf16* As = WcB + (size_t)(o0 + lr) * COU + lk;
#pragma unroll
        for (int kk = 0; kk < COU; kk += 32) {
            bf16x8 a[4], bb[4];
#pragma unroll
            for (int m = 0; m < 4; m++)
                a[m] = *(const bf16x8*)(As + (size_t)(m * 16) * COU + kk);
#pragma unroll
            for (int n = 0; n < 4; n++)
                bb[n] = *(const bf16x8*)(&g1s[n * 16 + lr][kk + lk]);
#pragma unroll
            for (int m = 0; m < 4; m++)
#pragma unroll
                for (int n = 0; n < 4; n++)
                    acc[m][n] = __builtin_amdgcn_mfma_f32_16x16x32_bf16(a[m], bb[n], acc[m][n], 0, 0, 0);
        }
#pragma unroll
        for (int m = 0; m < 4; m++) {
#pragma unroll
            for (int j = 0; j < 4; j++) {
                int o = o0 + m * 16 + rb + j;
                float bias = bc[o];
#pragma unroll
                for (int n = 0; n < 4; n++) {
                    int ncol = n0 + n * 16 + lr;
                    out[((size_t)b * COU + o) * NN + ncol] = acc[m][n][j] + bias;
                }
            }
        }
    }
}

extern "C" void kernel_launch(void* const* d_in, const int* in_sizes, int n_in,
                              void* d_out, int out_size, void* d_ws, size_t ws_size,
                              hipStream_t stream) {
    const float* xyz      = (const float*)d_in[0];
    const float* features = (const float*)d_in[1];
    const float* W_spec   = (const float*)d_in[2];
    const float* b_spec   = (const float*)d_in[3];
    const float* bn_gamma = (const float*)d_in[4];
    const float* bn_beta  = (const float*)d_in[5];
    const float* bn_mean  = (const float*)d_in[6];
    const float* bn_var   = (const float*)d_in[7];
    const float* W_low    = (const float*)d_in[8];
    const float* b_low    = (const float*)d_in[9];
    const float* W_high   = (const float*)d_in[10];
    const float* b_high   = (const float*)d_in[11];
    float* out = (float*)d_out;

    char* ws = (char*)d_ws;
    size_t off = 0;
    __bf16* fTB   = (__bf16*)(ws + off); off += (size_t)BB * NN * CINC * 2;      // 4 MB
    __bf16* specB = (__bf16*)(ws + off); off += (size_t)BB * NN * CINC * 2;      // 4 MB
    int*    idx   = (int*)(ws + off);    off += (size_t)BB * NN * KNNK * 4;      // 1 MB
    int*    rcnt  = (int*)(ws + off);    off += (size_t)BB * NN * 4;             // 64 KB
    int*    rev   = (int*)(ws + off);    off += (size_t)BB * NN * REVCAP * 4;    // 4 MB
    __bf16* WspecB= (__bf16*)(ws + off); off += (size_t)COU * CINC * 2;          // 64 KB
    __bf16* WcB   = (__bf16*)(ws + off); off += (size_t)COU * COU * 2;           // 128 KB
    float*  bc    = (float*)(ws + off);  off += (size_t)COU * 4;                 // 1 KB

    setup_kernel<<<dim3(2048 + 128), dim3(32, 8), 0, stream>>>(
        features, fTB, W_spec, W_low, W_high, b_low, b_high, WspecB, WcB, bc, rcnt);
    knn_fused_kernel<<<dim3(NN / QG, BB), dim3(1024), 0, stream>>>(xyz, idx, rcnt, rev);
    spec_kernel<<<dim3(BB * NN), dim3(128), 0, stream>>>(fTB, idx, rcnt, rev, specB);
    gemm12_fused<<<dim3(NN / 64, BB), dim3(256), 0, stream>>>(
        specB, WspecB, b_spec, bn_gamma, bn_beta, bn_mean, bn_var, WcB, bc, out);
}